// Round 3
// baseline (8123.159 us; speedup 1.0000x reference)
//
#include <hip/hip_runtime.h>
#include <cstdint>
#include <cstddef>

typedef _Float16 half_t;
typedef _Float16 half2_t __attribute__((ext_vector_type(2)));
typedef _Float16 half8_t __attribute__((ext_vector_type(8)));
typedef float   float4_t __attribute__((ext_vector_type(4)));

#define L_N 2
#define B_N 32
#define S_N 2048
#define H_N 256
#define G_N 1024            // 4H
#define M_N (B_N*S_N)       // 65536

// ---- fused recurrence geometry ----
// 256 blocks = 32 chains x 8 cell-slices; iteration t advances layer0 step t
// and layer1 step t-1 (software wavefront pipeline). 12 waves/block:
// waves 0-3 = L0 (8 cells each), waves 4-11 = L1 (4 cells each, K = h1||h0).
#define RING_R 4
#define RING_BYTES (B_N*RING_R*128*8)   // 128 KiB per ring

// ws layout (bytes)
#define WS_A0   0ull                 // fp16 [M][H]: layer-0 input (f32->f16)
#define WS_XP   33554432ull          // fp16 [M][G]: layer-0 input projection, packed [m][cell][4]
#define WS_WI   167772160ull         // fp16 [L][G][H]
#define WS_WH   168820736ull         // fp16 [L][G][H]
#define WS_BSUM 169869312ull         // f32 [L][G]  (b_ih + b_hh)
#define WS_HP0  169877504ull         // u64 ring [B][RING_R][128] tagged h0 pairs
#define WS_HP1  170008576ull         // u64 ring [B][RING_R][128] tagged h1 pairs

__global__ void cvt_f32_f16(const float* __restrict__ in, half_t* __restrict__ out, int n){
  int i = blockIdx.x*256 + threadIdx.x;
  if (i < n) out[i] = (half_t)in[i];
}

__global__ void make_bsum(const float* __restrict__ bi, const float* __restrict__ bh,
                          float* __restrict__ bs, int n){
  int i = blockIdx.x*256 + threadIdx.x;
  if (i < n) bs[i] = bi[i] + bh[i];
}

// XP[m, cell, gate] = sum_k A[m,k] * W[gate*256+cell, k] + bsum[...]
__global__ __launch_bounds__(256) void gemm_xp(
    const half_t* __restrict__ A, const half_t* __restrict__ W,
    const float* __restrict__ bsum, half_t* __restrict__ XP)
{
  const int wave = threadIdx.x >> 6;
  const int lane = threadIdx.x & 63;
  const int l15 = lane & 15, quad = lane >> 4;
  const int m0 = blockIdx.x*64 + wave*16;
  const int n0 = blockIdx.y*64;
  float4_t acc[4] = {{0,0,0,0},{0,0,0,0},{0,0,0,0},{0,0,0,0}};
  const half_t* arow = A + (size_t)(m0 + l15)*H_N + quad*8;
  const half_t* brow[4];
  #pragma unroll
  for (int nt=0; nt<4; ++nt)
    brow[nt] = W + (size_t)(n0 + nt*16 + l15)*H_N + quad*8;
  #pragma unroll
  for (int k0=0; k0<H_N; k0+=32){
    half8_t af = *(const half8_t*)(arow + k0);
    #pragma unroll
    for (int nt=0; nt<4; ++nt){
      half8_t bf = *(const half8_t*)(brow[nt] + k0);
      acc[nt] = __builtin_amdgcn_mfma_f32_16x16x32_f16(af, bf, acc[nt], 0, 0, 0);
    }
  }
  #pragma unroll
  for (int nt=0; nt<4; ++nt){
    const int col = n0 + nt*16 + l15;          // gate row g in [0,1024)
    const int cell = col & 255, gate = col >> 8;
    const float bs = bsum[col];
    #pragma unroll
    for (int r=0; r<4; ++r){
      XP[(size_t)(m0 + quad*4 + r)*G_N + cell*4 + gate] = (half_t)(acc[nt][r] + bs);
    }
  }
}

__device__ __forceinline__ float sigf(float x){ return 1.f/(1.f + __expf(-x)); }
__device__ __forceinline__ float tanh_f(float x){ return 1.f - 2.f/(__expf(2.f*x) + 1.f); }

// Lookahead-1 poll: issue the next load BEFORE waiting on the previous one,
// halving the effective poll period (dependent-load latency ~L3).
__device__ __forceinline__ uint32_t ring_poll(const unsigned long long* p, unsigned tag){
  unsigned long long a = __hip_atomic_load(p, __ATOMIC_RELAXED, __HIP_MEMORY_SCOPE_AGENT);
  for (;;){
    unsigned long long b = __hip_atomic_load(p, __ATOMIC_RELAXED, __HIP_MEMORY_SCOPE_AGENT);
    if ((unsigned)(a >> 32) == tag) return (uint32_t)a;
    a = b;
  }
}

// Raw barrier: orders LDS staging across waves WITHOUT draining outstanding
// global stores (what __syncthreads' vmcnt(0) would do). Memory clobbers pin
// compile-time ordering; s_barrier + lgkmcnt handle runtime.
__device__ __forceinline__ void wg_barrier_lds(){
  asm volatile("s_waitcnt lgkmcnt(0)" ::: "memory");
  __builtin_amdgcn_s_barrier();
  asm volatile("" ::: "memory");
}

// Fused 2-layer LSTM recurrence, wave-autonomous.
// hcat LDS buffer: [t&1][ h1 pairs 0..127 | h0 pairs 128..255 ].
// WAR on hcat is safe without extra barriers: staging iter t+2 (same parity)
// is gated on poll completion of local waves' iter-(t+1) publishes, which in
// program order follow their iter-t reads of this buffer.
__global__ __launch_bounds__(768) void lstm_fused(
    const uint32_t* __restrict__ Wh0,  // fp16-pair view [1024][128] layer0 Whh
    const uint32_t* __restrict__ Wh1,  // layer1 Whh
    const uint32_t* __restrict__ Wi1,  // layer1 Wih
    const half_t*  __restrict__ xp,    // [M][1024] packed [m][cell][4], biases folded
    const float*   __restrict__ bsum1, // [1024] layer1 bias sums
    unsigned long long* __restrict__ hp0,
    unsigned long long* __restrict__ hp1,
    float* __restrict__ out,           // [B][S][H] fp32 layer1 h sequence
    float* __restrict__ hT, float* __restrict__ cT)
{
  __shared__ __align__(16) uint32_t hcat[2][256];
  const int tid = threadIdx.x;
  const int wv  = tid >> 6;          // 0..11
  const int l   = tid & 63;
  const int b   = blockIdx.x & 31;
  const int s   = blockIdx.x >> 5;
  const bool isL0 = (wv < 4);

  // row geometry: L0 8 lanes/row, L1 16 lanes/row; 16 h-pairs per lane
  const int cw   = isL0 ? (l >> 3) : (l >> 4);
  const int kl   = isL0 ? (l & 7)  : (l & 15);
  const int cell = isL0 ? (s*32 + wv*8 + cw) : (s*32 + (wv-4)*4 + cw);
  const int hbase = isL0 ? (128 + kl*16) : (kl*16);   // u32 index into hcat row

  // VGPR-resident weights: wreg[p] = gate p's 16 pairs for this lane's K-slice
  uint4 wreg[4][4];
  {
    const uint32_t* mat; int koff;
    if (isL0)      { mat = Wh0; koff = kl*16; }
    else if (kl<8) { mat = Wh1; koff = kl*16; }
    else           { mat = Wi1; koff = (kl-8)*16; }
    #pragma unroll
    for (int p=0;p<4;++p){
      const uint32_t* rp = mat + (size_t)(p*256 + cell)*128 + koff;
      #pragma unroll
      for (int i=0;i<4;++i) wreg[p][i] = *(const uint4*)(rp + 4*i);
    }
  }

  // L1 biases (valid on kl==0 lanes)
  float bb0=0.f, bb1=0.f, bb2=0.f, bb3=0.f;
  if (!isL0 && kl==0){
    bb0 = bsum1[      cell];
    bb1 = bsum1[256 + cell];
    bb2 = bsum1[512 + cell];
    bb3 = bsum1[768 + cell];
  }

  unsigned long long* r0 = hp0 + (size_t)b*(RING_R*128);
  unsigned long long* r1 = hp1 + (size_t)b*(RING_R*128);
  const size_t base = (size_t)b * S_N;
  float cst = 0.f;

  for (int t=0; t<=S_N; ++t){
    // early xp load (L0 cell lanes) - in flight across poll+barrier
    uint2 xv = {0u,0u};
    if (isL0 && kl==0 && t < S_N)
      xv = *(const uint2*)(xp + (base+t)*G_N + (size_t)cell*4);

    // stage: waves 0,1 poll ring0 -> h0[t-1]; waves 2,3 poll ring1 -> h1[t-2]
    const int bufi = t & 1;
    if (wv < 2){
      const int a = wv*64 + l;
      uint32_t hv = 0u;
      if (t > 0) hv = ring_poll(r0 + (size_t)((t-1)&(RING_R-1))*128 + a, (unsigned)t);
      hcat[bufi][128 + a] = hv;
    } else if (wv < 4){
      const int a = (wv-2)*64 + l;
      uint32_t hv = 0u;
      if (t > 1) hv = ring_poll(r1 + (size_t)((t-2)&(RING_R-1))*128 + a, (unsigned)(t-1));
      hcat[bufi][a] = hv;
    }
    wg_barrier_lds();

    const bool active = isL0 ? (t < S_N) : (t >= 1);
    if (active){
      // my 16 h pairs (reused across all 4 gate passes)
      const uint4* hsrc = (const uint4*)&hcat[bufi][hbase];
      const uint4 hh0 = hsrc[0], hh1 = hsrc[1], hh2 = hsrc[2], hh3 = hsrc[3];

      float gate[4];
      #pragma unroll
      for (int p=0;p<4;++p){
        float a0=0.f,a1=0.f,a2=0.f,a3=0.f;
        {
          const uint4 ww = wreg[p][0];
          a0 = __builtin_amdgcn_fdot2(__builtin_bit_cast(half2_t, ww.x), __builtin_bit_cast(half2_t, hh0.x), a0, false);
          a1 = __builtin_amdgcn_fdot2(__builtin_bit_cast(half2_t, ww.y), __builtin_bit_cast(half2_t, hh0.y), a1, false);
          a2 = __builtin_amdgcn_fdot2(__builtin_bit_cast(half2_t, ww.z), __builtin_bit_cast(half2_t, hh0.z), a2, false);
          a3 = __builtin_amdgcn_fdot2(__builtin_bit_cast(half2_t, ww.w), __builtin_bit_cast(half2_t, hh0.w), a3, false);
        }
        {
          const uint4 ww = wreg[p][1];
          a0 = __builtin_amdgcn_fdot2(__builtin_bit_cast(half2_t, ww.x), __builtin_bit_cast(half2_t, hh1.x), a0, false);
          a1 = __builtin_amdgcn_fdot2(__builtin_bit_cast(half2_t, ww.y), __builtin_bit_cast(half2_t, hh1.y), a1, false);
          a2 = __builtin_amdgcn_fdot2(__builtin_bit_cast(half2_t, ww.z), __builtin_bit_cast(half2_t, hh1.z), a2, false);
          a3 = __builtin_amdgcn_fdot2(__builtin_bit_cast(half2_t, ww.w), __builtin_bit_cast(half2_t, hh1.w), a3, false);
        }
        {
          const uint4 ww = wreg[p][2];
          a0 = __builtin_amdgcn_fdot2(__builtin_bit_cast(half2_t, ww.x), __builtin_bit_cast(half2_t, hh2.x), a0, false);
          a1 = __builtin_amdgcn_fdot2(__builtin_bit_cast(half2_t, ww.y), __builtin_bit_cast(half2_t, hh2.y), a1, false);
          a2 = __builtin_amdgcn_fdot2(__builtin_bit_cast(half2_t, ww.z), __builtin_bit_cast(half2_t, hh2.z), a2, false);
          a3 = __builtin_amdgcn_fdot2(__builtin_bit_cast(half2_t, ww.w), __builtin_bit_cast(half2_t, hh2.w), a3, false);
        }
        {
          const uint4 ww = wreg[p][3];
          a0 = __builtin_amdgcn_fdot2(__builtin_bit_cast(half2_t, ww.x), __builtin_bit_cast(half2_t, hh3.x), a0, false);
          a1 = __builtin_amdgcn_fdot2(__builtin_bit_cast(half2_t, ww.y), __builtin_bit_cast(half2_t, hh3.y), a1, false);
          a2 = __builtin_amdgcn_fdot2(__builtin_bit_cast(half2_t, ww.z), __builtin_bit_cast(half2_t, hh3.z), a2, false);
          a3 = __builtin_amdgcn_fdot2(__builtin_bit_cast(half2_t, ww.w), __builtin_bit_cast(half2_t, hh3.w), a3, false);
        }
        float v = (a0+a1)+(a2+a3);
        v += __shfl_xor(v, 1, 64);
        v += __shfl_xor(v, 2, 64);
        v += __shfl_xor(v, 4, 64);
        if (!isL0) v += __shfl_xor(v, 8, 64);
        gate[p] = v;
      }

      float s0,s1,s2,s3;
      if (isL0){
        const half2_t xlo = __builtin_bit_cast(half2_t, xv.x);
        const half2_t xhi = __builtin_bit_cast(half2_t, xv.y);
        s0 = gate[0] + (float)xlo.x;
        s1 = gate[1] + (float)xlo.y;
        s2 = gate[2] + (float)xhi.x;
        s3 = gate[3] + (float)xhi.y;
      } else {
        s0 = gate[0] + bb0; s1 = gate[1] + bb1;
        s2 = gate[2] + bb2; s3 = gate[3] + bb3;
      }
      const float gi = sigf(s0);
      const float gf = sigf(s1);
      const float gg = tanh_f(s2);
      const float go = sigf(s3);
      cst = gf*cst + gi*gg;
      const float h = go * tanh_f(cst);
      const half_t hv16 = (half_t)h;
      const int hu = (int)__builtin_bit_cast(unsigned short, hv16);

      if (isL0){
        const int phi = __shfl(hu, (l + 8) & 63, 64);   // partner cell (kl==0 lane)
        if ((l & 15) == 0){
          const int j = l >> 4;
          const unsigned long long val =
              ((unsigned long long)(unsigned)(t+1) << 32)
            | (unsigned long long)((((unsigned)phi & 0xffffu) << 16) | ((unsigned)hu & 0xffffu));
          __hip_atomic_store(r0 + (size_t)(t&(RING_R-1))*128 + s*16 + wv*4 + j, val,
                             __ATOMIC_RELAXED, __HIP_MEMORY_SCOPE_AGENT);
        }
        if (kl == 0 && t == S_N-1){ hT[b*H_N + cell] = h; cT[b*H_N + cell] = cst; }
      } else {
        const int phi = __shfl(hu, (l + 16) & 63, 64);
        if ((l & 31) == 0){
          const int j = l >> 5;
          const unsigned long long val =
              ((unsigned long long)(unsigned)t << 32)
            | (unsigned long long)((((unsigned)phi & 0xffffu) << 16) | ((unsigned)hu & 0xffffu));
          __hip_atomic_store(r1 + (size_t)((t-1)&(RING_R-1))*128 + s*16 + (wv-4)*2 + j, val,
                             __ATOMIC_RELAXED, __HIP_MEMORY_SCOPE_AGENT);
        }
        if (kl == 0){
          out[(base + (t-1))*H_N + cell] = h;
          if (t == S_N){ hT[B_N*H_N + b*H_N + cell] = h; cT[B_N*H_N + b*H_N + cell] = cst; }
        }
      }
    }
  }
}

extern "C" void kernel_launch(void* const* d_in, const int* in_sizes, int n_in,
                              void* d_out, int out_size, void* d_ws, size_t ws_size,
                              hipStream_t stream)
{
  const float* x   = (const float*)d_in[0];
  const float* Wih = (const float*)d_in[1];
  const float* bih = (const float*)d_in[2];
  const float* Whh = (const float*)d_in[3];
  const float* bhh = (const float*)d_in[4];
  float* out = (float*)d_out;

  char* ws = (char*)d_ws;
  half_t* A0   = (half_t*)(ws + WS_A0);
  half_t* XP   = (half_t*)(ws + WS_XP);
  half_t* Wi16 = (half_t*)(ws + WS_WI);
  half_t* Wh16 = (half_t*)(ws + WS_WH);
  float*  bsum = (float*)(ws + WS_BSUM);
  unsigned long long* hp0 = (unsigned long long*)(ws + WS_HP0);
  unsigned long long* hp1 = (unsigned long long*)(ws + WS_HP1);

  cvt_f32_f16<<<dim3(M_N*H_N/256), dim3(256), 0, stream>>>(x, A0, M_N*H_N);
  cvt_f32_f16<<<dim3(L_N*G_N*H_N/256), dim3(256), 0, stream>>>(Wih, Wi16, L_N*G_N*H_N);
  cvt_f32_f16<<<dim3(L_N*G_N*H_N/256), dim3(256), 0, stream>>>(Whh, Wh16, L_N*G_N*H_N);
  make_bsum<<<dim3(L_N*G_N/256), dim3(256), 0, stream>>>(bih, bhh, bsum, L_N*G_N);

  float* hT = out + (size_t)M_N*H_N;       // hs [2][32][256]
  float* cT = hT + (size_t)L_N*B_N*H_N;    // cs [2][32][256]

  // layer-0 input projection (layer-1's is fused into the recurrence kernel)
  gemm_xp<<<dim3(M_N/64, G_N/64), dim3(256), 0, stream>>>(A0, Wi16, bsum, XP);

  hipMemsetAsync(hp0, 0, 2*RING_BYTES, stream);   // hp0 + hp1 contiguous

  lstm_fused<<<dim3(B_N*8), dim3(768), 0, stream>>>(
      (const uint32_t*)Wh16,
      (const uint32_t*)(Wh16 + (size_t)G_N*H_N),
      (const uint32_t*)(Wi16 + (size_t)G_N*H_N),
      XP, bsum + G_N, hp0, hp1, out, hT, cT);
}

// Round 4
// 3954.548 us; speedup vs baseline: 2.0541x; 2.0541x over previous
//
#include <hip/hip_runtime.h>
#include <cstdint>
#include <cstddef>

typedef _Float16 half_t;
typedef _Float16 half2_t __attribute__((ext_vector_type(2)));
typedef _Float16 half8_t __attribute__((ext_vector_type(8)));
typedef float   float4_t __attribute__((ext_vector_type(4)));

#define L_N 2
#define B_N 32
#define S_N 2048
#define H_N 256
#define G_N 1024            // 4H
#define M_N (B_N*S_N)       // 65536

// ---- fused recurrence geometry (round-2 structure, proven 0-conflict) ----
// 256 blocks = 32 chains x 8 cell-slices; iteration t advances layer0 step t
// and layer1 step t-1. 768 threads in 6 parts of 128:
// parts 0,1 = Wh0 K-halves; 2,3 = Wh1; 4,5 = Wi1 (fused layer-1 x-projection).
#define RING_R 4
#define RING_BYTES (B_N*RING_R*128*8)   // 128 KiB per ring

// ws layout (bytes)
#define WS_A0   0ull                 // fp16 [M][H]: layer-0 input (f32->f16)
#define WS_XP   33554432ull          // fp16 [M][G]: layer-0 input projection, packed [m][cell][4]
#define WS_WI   167772160ull         // fp16 [L][G][H]
#define WS_WH   168820736ull         // fp16 [L][G][H]
#define WS_BSUM 169869312ull         // f32 [L][G]  (b_ih + b_hh)
#define WS_HP0  169877504ull         // u64 ring [B][RING_R][128] tagged h0 pairs
#define WS_HP1  170008576ull         // u64 ring [B][RING_R][128] tagged h1 pairs

__global__ void cvt_f32_f16(const float* __restrict__ in, half_t* __restrict__ out, int n){
  int i = blockIdx.x*256 + threadIdx.x;
  if (i < n) out[i] = (half_t)in[i];
}

__global__ void make_bsum(const float* __restrict__ bi, const float* __restrict__ bh,
                          float* __restrict__ bs, int n){
  int i = blockIdx.x*256 + threadIdx.x;
  if (i < n) bs[i] = bi[i] + bh[i];
}

// XP[m, cell, gate] = sum_k A[m,k] * W[gate*256+cell, k] + bsum[...]
__global__ __launch_bounds__(256) void gemm_xp(
    const half_t* __restrict__ A, const half_t* __restrict__ W,
    const float* __restrict__ bsum, half_t* __restrict__ XP)
{
  const int wave = threadIdx.x >> 6;
  const int lane = threadIdx.x & 63;
  const int l15 = lane & 15, quad = lane >> 4;
  const int m0 = blockIdx.x*64 + wave*16;
  const int n0 = blockIdx.y*64;
  float4_t acc[4] = {{0,0,0,0},{0,0,0,0},{0,0,0,0},{0,0,0,0}};
  const half_t* arow = A + (size_t)(m0 + l15)*H_N + quad*8;
  const half_t* brow[4];
  #pragma unroll
  for (int nt=0; nt<4; ++nt)
    brow[nt] = W + (size_t)(n0 + nt*16 + l15)*H_N + quad*8;
  #pragma unroll
  for (int k0=0; k0<H_N; k0+=32){
    half8_t af = *(const half8_t*)(arow + k0);
    #pragma unroll
    for (int nt=0; nt<4; ++nt){
      half8_t bf = *(const half8_t*)(brow[nt] + k0);
      acc[nt] = __builtin_amdgcn_mfma_f32_16x16x32_f16(af, bf, acc[nt], 0, 0, 0);
    }
  }
  #pragma unroll
  for (int nt=0; nt<4; ++nt){
    const int col = n0 + nt*16 + l15;          // gate row g in [0,1024)
    const int cell = col & 255, gate = col >> 8;
    const float bs = bsum[col];
    #pragma unroll
    for (int r=0; r<4; ++r){
      XP[(size_t)(m0 + quad*4 + r)*G_N + cell*4 + gate] = (half_t)(acc[nt][r] + bs);
    }
  }
}

__device__ __forceinline__ float sigf(float x){ return 1.f/(1.f + __expf(-x)); }
__device__ __forceinline__ float tanh_f(float x){ return 1.f - 2.f/(__expf(2.f*x) + 1.f); }

__device__ __forceinline__ uint32_t ring_poll(const unsigned long long* p, unsigned tag){
  unsigned long long v;
  do { v = __hip_atomic_load(p, __ATOMIC_RELAXED, __HIP_MEMORY_SCOPE_AGENT); }
  while ((unsigned)(v >> 32) != tag);
  return (uint32_t)v;
}

// Raw barrier: orders LDS staging across waves WITHOUT draining outstanding
// global stores/loads (what __syncthreads' vmcnt(0) would do - that drain put
// publish/out store-ack latency on the serial path twice per iteration).
// Memory clobbers pin compile-time ordering; lgkmcnt(0)+s_barrier handle
// runtime LDS visibility (LDS is CU-local).
__device__ __forceinline__ void wg_barrier_lds(){
  asm volatile("s_waitcnt lgkmcnt(0)" ::: "memory");
  __builtin_amdgcn_s_barrier();
  asm volatile("" ::: "memory");
}

// Fused 2-layer LSTM recurrence (round-2 data layout, raw LDS barriers,
// finisher split across waves 0 and 1).
// Cross-block h exchange: one u64 atom = {tag | 2xfp16}, relaxed agent-scope
// atomics, 4-slot rings; publisher reaching iter t implies all peers finished
// iter t-1, so slot reuse at t+4 never races a lagging reader (proven r1-r3).
// WAR on h0s/h1s/red without trailing barrier: readers of h0s/h1s finish
// before B2(t), writers write after B2(t) in phase-1(t+1); red readers
// (finisher waves, phase-3(t)) finish before B1(t+1), red writers write after
// B1(t+1) in phase-2(t+1).
__global__ __launch_bounds__(768) void lstm_fused(
    const uint32_t* __restrict__ Wh0,  // fp16-pair view [1024][128] layer0 Whh
    const uint32_t* __restrict__ Wh1,  // layer1 Whh
    const uint32_t* __restrict__ Wi1,  // layer1 Wih
    const half_t*  __restrict__ xp,    // [M][1024] packed [m][cell][4], biases folded
    const float*   __restrict__ bsum1, // [1024] layer1 bias sums
    unsigned long long* __restrict__ hp0,
    unsigned long long* __restrict__ hp1,
    float* __restrict__ out,           // [B][S][H] fp32 layer1 h sequence
    float* __restrict__ hT, float* __restrict__ cT)
{
  __shared__ __align__(16) uint32_t h0s[128];  // h0[t-1] pairs
  __shared__ __align__(16) uint32_t h1s[128];  // h1[t-2] pairs
  __shared__ float red[6][128];
  const int tid = threadIdx.x;
  const int part = tid >> 7;       // 0..5
  const int r    = tid & 127;      // row in slice: gate g = r>>5, cell cl = r&31
  const int kh   = part & 1;       // K-half
  const int b  = blockIdx.x & 31;
  const int s  = blockIdx.x >> 5;
  const int g  = r >> 5;
  const int cl = r & 31;
  const int cell = s*32 + cl;

  // VGPR-resident weights: row (g*256+cell) of my matrix, pairs [kh*64, kh*64+64)
  const uint32_t* wbase =
      (part < 2 ? Wh0 : (part < 4 ? Wh1 : Wi1)) + (size_t)(g*256 + cell)*128 + kh*64;
  uint32_t w[64];
  #pragma unroll
  for (int i=0;i<64;++i) w[i] = wbase[i];

  // L1 finisher = wave1 lanes 0-31 (tid 64..95): biases + c-state
  float bb0=0.f, bb1=0.f, bb2=0.f, bb3=0.f;
  if (tid >= 64 && tid < 96){
    const int mc = s*32 + (tid - 64);
    bb0 = bsum1[      mc];
    bb1 = bsum1[256 + mc];
    bb2 = bsum1[512 + mc];
    bb3 = bsum1[768 + mc];
  }

  unsigned long long* r0 = hp0 + (size_t)b*(RING_R*128);
  unsigned long long* r1 = hp1 + (size_t)b*(RING_R*128);
  const size_t base = (size_t)b * S_N;
  float cst = 0.f;   // wave0 lanes0-31: layer0 c; wave1 lanes0-31: layer1 c

  for (int t=0; t<=S_N; ++t){
    // ---- phase 1: xp prefetch (wave0 lanes 0-31) + ring polls -> LDS stage
    uint2 xv = {0u,0u};
    if (tid < 32 && t < S_N)
      xv = *(const uint2*)(xp + (base + t)*G_N + (size_t)(s*32 + tid)*4);
    if (tid < 128){
      uint32_t hv = 0u;
      if (t > 0) hv = ring_poll(r0 + (size_t)((t-1)&(RING_R-1))*128 + tid, (unsigned)t);
      h0s[tid] = hv;
    } else if (tid < 256){
      const int j = tid - 128;
      uint32_t hv = 0u;
      if (t > 1) hv = ring_poll(r1 + (size_t)((t-2)&(RING_R-1))*128 + j, (unsigned)(t-1));
      h1s[j] = hv;
    }
    wg_barrier_lds();                   // B1: h staged (LDS-only barrier)

    // ---- phase 2: fdot (64 pair-MACs per thread, 4 independent streams)
    const bool active = (part < 2) ? (t < S_N) : (t >= 1);
    if (active){
      const uint32_t* hsrc = (part == 2 || part == 3) ? h1s : h0s;
      const uint4* h4 = (const uint4*)(hsrc + kh*64);
      float a0=0.f,a1=0.f,a2=0.f,a3=0.f;
      #pragma unroll
      for (int i=0;i<16;++i){
        const uint4 hh = h4[i];
        a0 = __builtin_amdgcn_fdot2(__builtin_bit_cast(half2_t, w[4*i+0]), __builtin_bit_cast(half2_t, hh.x), a0, false);
        a1 = __builtin_amdgcn_fdot2(__builtin_bit_cast(half2_t, w[4*i+1]), __builtin_bit_cast(half2_t, hh.y), a1, false);
        a2 = __builtin_amdgcn_fdot2(__builtin_bit_cast(half2_t, w[4*i+2]), __builtin_bit_cast(half2_t, hh.z), a2, false);
        a3 = __builtin_amdgcn_fdot2(__builtin_bit_cast(half2_t, w[4*i+3]), __builtin_bit_cast(half2_t, hh.w), a3, false);
      }
      red[part][r] = (a0+a1)+(a2+a3);
    }
    wg_barrier_lds();                   // B2: partials visible (LDS-only)

    // ---- phase 3a: wave0 lanes 0-31 finish layer0 step t
    if (tid < 32){
      if (t < S_N){
        const int l = tid;
        const half2_t xlo = __builtin_bit_cast(half2_t, xv.x);
        const half2_t xhi = __builtin_bit_cast(half2_t, xv.y);
        const float s0 = red[0][     l] + red[1][     l] + (float)xlo.x;
        const float s1 = red[0][32 + l] + red[1][32 + l] + (float)xlo.y;
        const float s2 = red[0][64 + l] + red[1][64 + l] + (float)xhi.x;
        const float s3 = red[0][96 + l] + red[1][96 + l] + (float)xhi.y;
        const float gi = sigf(s0);
        const float gf = sigf(s1);
        const float gg = tanh_f(s2);
        const float go = sigf(s3);
        cst = gf*cst + gi*gg;
        const float h = go * tanh_f(cst);
        const half_t hv16 = (half_t)h;
        const int hu = (int)__builtin_bit_cast(unsigned short, hv16);
        const int plo = __shfl(hu, 2*l,   64);
        const int phi = __shfl(hu, 2*l+1, 64);
        if (l < 16){
          const unsigned long long val =
              ((unsigned long long)(unsigned)(t+1) << 32)
            | (unsigned long long)((((unsigned)phi & 0xffffu) << 16) | ((unsigned)plo & 0xffffu));
          __hip_atomic_store(r0 + (size_t)(t&(RING_R-1))*128 + s*16 + l, val,
                             __ATOMIC_RELAXED, __HIP_MEMORY_SCOPE_AGENT);
        }
        if (t == S_N-1){ hT[b*H_N + s*32 + l] = h; cT[b*H_N + s*32 + l] = cst; }
      }
    }
    // ---- phase 3b: wave1 lanes 0-31 finish layer1 step t-1 (concurrent)
    else if (tid >= 64 && tid < 96){
      if (t >= 1){
        const int l = tid - 64;
        const int mc = s*32 + l;
        const float s0 = red[2][     l] + red[3][     l] + red[4][     l] + red[5][     l] + bb0;
        const float s1 = red[2][32 + l] + red[3][32 + l] + red[4][32 + l] + red[5][32 + l] + bb1;
        const float s2 = red[2][64 + l] + red[3][64 + l] + red[4][64 + l] + red[5][64 + l] + bb2;
        const float s3 = red[2][96 + l] + red[3][96 + l] + red[4][96 + l] + red[5][96 + l] + bb3;
        const float gi = sigf(s0);
        const float gf = sigf(s1);
        const float gg = tanh_f(s2);
        const float go = sigf(s3);
        cst = gf*cst + gi*gg;
        const float h = go * tanh_f(cst);
        const half_t hv16 = (half_t)h;
        const int hu = (int)__builtin_bit_cast(unsigned short, hv16);
        const int plo = __shfl(hu, 2*l,   64);
        const int phi = __shfl(hu, 2*l+1, 64);
        if (l < 16){
          const unsigned long long val =
              ((unsigned long long)(unsigned)t << 32)
            | (unsigned long long)((((unsigned)phi & 0xffffu) << 16) | ((unsigned)plo & 0xffffu));
          __hip_atomic_store(r1 + (size_t)((t-1)&(RING_R-1))*128 + s*16 + l, val,
                             __ATOMIC_RELAXED, __HIP_MEMORY_SCOPE_AGENT);
        }
        out[(base + (t-1))*H_N + mc] = h;
        if (t == S_N){ hT[B_N*H_N + b*H_N + mc] = h; cT[B_N*H_N + b*H_N + mc] = cst; }
      }
    }
    // no trailing barrier (see WAR argument above)
  }
}

extern "C" void kernel_launch(void* const* d_in, const int* in_sizes, int n_in,
                              void* d_out, int out_size, void* d_ws, size_t ws_size,
                              hipStream_t stream)
{
  const float* x   = (const float*)d_in[0];
  const float* Wih = (const float*)d_in[1];
  const float* bih = (const float*)d_in[2];
  const float* Whh = (const float*)d_in[3];
  const float* bhh = (const float*)d_in[4];
  float* out = (float*)d_out;

  char* ws = (char*)d_ws;
  half_t* A0   = (half_t*)(ws + WS_A0);
  half_t* XP   = (half_t*)(ws + WS_XP);
  half_t* Wi16 = (half_t*)(ws + WS_WI);
  half_t* Wh16 = (half_t*)(ws + WS_WH);
  float*  bsum = (float*)(ws + WS_BSUM);
  unsigned long long* hp0 = (unsigned long long*)(ws + WS_HP0);
  unsigned long long* hp1 = (unsigned long long*)(ws + WS_HP1);

  cvt_f32_f16<<<dim3(M_N*H_N/256), dim3(256), 0, stream>>>(x, A0, M_N*H_N);
  cvt_f32_f16<<<dim3(L_N*G_N*H_N/256), dim3(256), 0, stream>>>(Wih, Wi16, L_N*G_N*H_N);
  cvt_f32_f16<<<dim3(L_N*G_N*H_N/256), dim3(256), 0, stream>>>(Whh, Wh16, L_N*G_N*H_N);
  make_bsum<<<dim3(L_N*G_N/256), dim3(256), 0, stream>>>(bih, bhh, bsum, L_N*G_N);

  float* hT = out + (size_t)M_N*H_N;       // hs [2][32][256]
  float* cT = hT + (size_t)L_N*B_N*H_N;    // cs [2][32][256]

  // layer-0 input projection (layer-1's is fused into the recurrence kernel)
  gemm_xp<<<dim3(M_N/64, G_N/64), dim3(256), 0, stream>>>(A0, Wi16, bsum, XP);

  hipMemsetAsync(hp0, 0, 2*RING_BYTES, stream);   // hp0 + hp1 contiguous

  lstm_fused<<<dim3(B_N*8), dim3(768), 0, stream>>>(
      (const uint32_t*)Wh16,
      (const uint32_t*)(Wh16 + (size_t)G_N*H_N),
      (const uint32_t*)(Wi16 + (size_t)G_N*H_N),
      XP, bsum + G_N, hp0, hp1, out, hT, cT);
}